// Round 4
// baseline (779.157 us; speedup 1.0000x reference)
//
#include <hip/hip_runtime.h>
#include <math.h>

// FusionNeRF round 4 (= round-3 design, compile fix):
//  - nerf_enc: positional encodings -> global bf16 Eg[M][128] (zero-padded cols 99..127)
//  - nerf_mlp_g: MFMA MLP, A(layer0) from global Eg, LDS = 36.1 KB -> 4 blocks/CU.
//    Swapped-operand MFMA (D^T) => packed ds_write_b64 epilogue.
//  - nerf_mlp_l: fallback (enc in LDS) if ws_size too small for Eg.
//  - nerf_comp: wave-per-ray shuffle-scan compositing.

#define RAYS 2048
#define SAMP 128
#define MTOT (RAYS * SAMP)
#define HD   256
#define BM   64              // samples per block
#define ES   136             // enc LDS stride (fallback kernel)
#define HS   264             // hidden LDS stride (bf16), 256 + 8 pad

#define OUT_RGB   0
#define OUT_DEPTH 6144
#define OUT_W     8192
#define OUT_SW    270336
#define OUT_DW    532480

// bf16 weight workspace offsets (elements)
#define SW0 0
#define SW1 32768
#define SW2 98304
#define SW3 163840
#define SW4 229376
#define DW0 233472
#define DW1 266240
#define DW2 331776
#define DW3 397312
#define DW4 462848
#define WTOT 466944

typedef __attribute__((ext_vector_type(8))) short short8;
typedef __attribute__((ext_vector_type(4))) float f32x4;

__device__ __forceinline__ float sigm(float x) { return 1.0f / (1.0f + expf(-x)); }

__device__ __forceinline__ unsigned bfbits(float f) {  // RNE fp32 -> bf16 bits
    union { float f; unsigned u; } v; v.f = f;
    unsigned r = v.u + 0x7fffu + ((v.u >> 16) & 1u);
    return r >> 16;
}
__device__ __forceinline__ short f2bf(float f) { return (short)bfbits(f); }
__device__ __forceinline__ unsigned pk2(float a, float b) {  // packed bf16 pair (a=low)
    return bfbits(a) | (bfbits(b) << 16);
}

// ---------------- weight prep: W[K][N] fp32 -> Wt[Npad][Kpad] bf16 ----------------
__device__ __forceinline__ void conv1(const float* __restrict__ src, short* __restrict__ dst,
                                      int local, int K, int N, int Kpad) {
    const int n = local / Kpad, k = local - n * Kpad;
    const float v = (k < K && n < N) ? src[k * N + n] : 0.0f;
    dst[local] = f2bf(v);
}

__global__ __launch_bounds__(256)
void prep_weights(const float* sW0, const float* sW1, const float* sW2,
                  const float* sW3, const float* sW4,
                  const float* dW0, const float* dW1, const float* dW2,
                  const float* dW3, const float* dW4, short* __restrict__ dst)
{
    const int idx = blockIdx.x * 256 + threadIdx.x;
    if (idx >= WTOT) return;
    if      (idx < SW1) conv1(sW0, dst + SW0, idx - SW0,  90, 256, 128);
    else if (idx < SW2) conv1(sW1, dst + SW1, idx - SW1, 256, 256, 256);
    else if (idx < SW3) conv1(sW2, dst + SW2, idx - SW2, 256, 256, 256);
    else if (idx < SW4) conv1(sW3, dst + SW3, idx - SW3, 256, 256, 256);
    else if (idx < DW0) conv1(sW4, dst + SW4, idx - SW4, 256,   4, 256);
    else if (idx < DW1) conv1(dW0, dst + DW0, idx - DW0,  99, 256, 128);
    else if (idx < DW2) conv1(dW1, dst + DW1, idx - DW1, 256, 256, 256);
    else if (idx < DW3) conv1(dW2, dst + DW2, idx - DW2, 256, 256, 256);
    else if (idx < DW4) conv1(dW3, dst + DW3, idx - DW3, 256, 256, 256);
    else                conv1(dW4, dst + DW4, idx - DW4, 256,   5, 256);
}

// ---------------- positional encoding value ----------------
__device__ __forceinline__ float encval(int d, int m,
                                        const float* __restrict__ points,
                                        const float* __restrict__ dirsv,
                                        const float* __restrict__ timev)
{
    float v = 0.0f;
    if (d < 3) {
        v = points[m * 3 + d];
    } else if (d < 63) {
        int qq = d - 3;
        const int l = qq / 6, r = qq - l * 6;
        const int c = (r < 3) ? r : r - 3;
        const float x = points[m * 3 + c] * (float)(1 << l);
        v = (r < 3) ? sinf(x) : cosf(x);
    } else if (d < 90) {
        int qq = d - 63;
        if (qq < 3) v = dirsv[m * 3 + qq];
        else {
            qq -= 3;
            const int l = qq / 6, r = qq - l * 6;
            const int c = (r < 3) ? r : r - 3;
            const float x = dirsv[m * 3 + c] * (float)(1 << l);
            v = (r < 3) ? sinf(x) : cosf(x);
        }
    } else if (d < 99) {
        int qq = d - 90;
        const float t = timev[m];
        if (qq == 0) v = t;
        else {
            qq -= 1;
            const float x = t * (float)(1 << (qq >> 1));
            v = ((qq & 1) == 0) ? sinf(x) : cosf(x);
        }
    }
    return v;
}

__global__ __launch_bounds__(256)
void nerf_enc(const float* __restrict__ points, const float* __restrict__ dirsv,
              const float* __restrict__ timev, short* __restrict__ Eg)
{
    const int idx = blockIdx.x * 256 + threadIdx.x;   // one per (m, d-pair)
    if (idx >= MTOT * 64) return;
    const int m = idx >> 6, dp = idx & 63;
    const float v0 = encval(2 * dp,     m, points, dirsv, timev);
    const float v1 = encval(2 * dp + 1, m, points, dirsv, timev);
    *(unsigned*)(Eg + (size_t)m * 128 + 2 * dp) = pk2(v0, v1);
}

// ---------------- epilogue: D^T accumulators -> Hb[m][n] packed b64 stores ----------------
template <bool RELU>
__device__ __forceinline__ void epilogue(f32x4 acc[4][4], const float* __restrict__ bias,
                                         short* O, int w, int q, int col)
{
    float4 bv[4];
#pragma unroll
    for (int nt = 0; nt < 4; nt++)
        bv[nt] = *(const float4*)(bias + w * 64 + nt * 16 + q * 4);
#pragma unroll
    for (int mt = 0; mt < 4; mt++) {
        short* dst = O + (mt * 16 + col) * HS + w * 64 + q * 4;
#pragma unroll
        for (int nt = 0; nt < 4; nt++) {
            float v0 = acc[mt][nt][0] + bv[nt].x;
            float v1 = acc[mt][nt][1] + bv[nt].y;
            float v2 = acc[mt][nt][2] + bv[nt].z;
            float v3 = acc[mt][nt][3] + bv[nt].w;
            if (RELU) {
                v0 = fmaxf(v0, 0.f); v1 = fmaxf(v1, 0.f);
                v2 = fmaxf(v2, 0.f); v3 = fmaxf(v3, 0.f);
            }
            uint2 p; p.x = pk2(v0, v1); p.y = pk2(v2, v3);
            *(uint2*)(dst + nt * 16) = p;
        }
    }
}

// A from LDS (stride As). Swapped-operand MFMA: acc = D^T tiles.
template <int KSTEPS, bool RELU>
__device__ __forceinline__ void layerL(const short* A, int As,
                                       const short* __restrict__ Wt,
                                       const float* __restrict__ bias,
                                       short* O, int tid)
{
    const int w = tid >> 6, lane = tid & 63, q = lane >> 4, col = lane & 15;
    const int K = KSTEPS * 32;
    f32x4 acc[4][4];
#pragma unroll
    for (int mt = 0; mt < 4; mt++)
#pragma unroll
        for (int nt = 0; nt < 4; nt++) acc[mt][nt] = (f32x4)0.0f;

    const short* wbase = Wt + (size_t)(w * 64) * K + q * 8;
#pragma unroll
    for (int kk = 0; kk < KSTEPS; kk++) {
        short8 a[4], b[4];
#pragma unroll
        for (int mt = 0; mt < 4; mt++)
            a[mt] = *(const short8*)(A + (mt * 16 + col) * As + kk * 32 + q * 8);
#pragma unroll
        for (int nt = 0; nt < 4; nt++)
            b[nt] = *(const short8*)(wbase + (size_t)(nt * 16 + col) * K + kk * 32);
#pragma unroll
        for (int mt = 0; mt < 4; mt++)
#pragma unroll
            for (int nt = 0; nt < 4; nt++)
                acc[mt][nt] = __builtin_amdgcn_mfma_f32_16x16x32_bf16(b[nt], a[mt], acc[mt][nt], 0, 0, 0);
    }
    __syncthreads();                       // all waves done reading A (A may alias O)
    epilogue<RELU>(acc, bias, O, w, q, col);
    __syncthreads();                       // O visible to next layer
}

// A from global (stride 128, Kpad=128 => KSTEPS=4).
template <bool RELU>
__device__ __forceinline__ void layerG(const short* __restrict__ Ag,
                                       const short* __restrict__ Wt,
                                       const float* __restrict__ bias,
                                       short* O, int tid)
{
    const int w = tid >> 6, lane = tid & 63, q = lane >> 4, col = lane & 15;
    f32x4 acc[4][4];
#pragma unroll
    for (int mt = 0; mt < 4; mt++)
#pragma unroll
        for (int nt = 0; nt < 4; nt++) acc[mt][nt] = (f32x4)0.0f;

    const short* wbase = Wt + (size_t)(w * 64) * 128 + q * 8;
#pragma unroll
    for (int kk = 0; kk < 4; kk++) {
        short8 a[4], b[4];
#pragma unroll
        for (int mt = 0; mt < 4; mt++)
            a[mt] = *(const short8*)(Ag + (size_t)(mt * 16 + col) * 128 + kk * 32 + q * 8);
#pragma unroll
        for (int nt = 0; nt < 4; nt++)
            b[nt] = *(const short8*)(wbase + (size_t)(nt * 16 + col) * 128 + kk * 32);
#pragma unroll
        for (int mt = 0; mt < 4; mt++)
#pragma unroll
            for (int nt = 0; nt < 4; nt++)
                acc[mt][nt] = __builtin_amdgcn_mfma_f32_16x16x32_bf16(b[nt], a[mt], acc[mt][nt], 0, 0, 0);
    }
    __syncthreads();                       // prior readers of O (e.g. static head) done
    epilogue<RELU>(acc, bias, O, w, q, col);
    __syncthreads();
}

// head: A[64][256] @ Wt[16][256]^T -> Out[64][NV] (+bias); normal operand order.
template <int NV>
__device__ __forceinline__ void head256(const short* A, int As,
                                        const short* __restrict__ Wt,
                                        const float* __restrict__ bias,
                                        float* Out, int tid)
{
    const int w = tid >> 6, lane = tid & 63, q = lane >> 4, col = lane & 15;
    f32x4 acc = (f32x4)0.0f;
#pragma unroll
    for (int kk = 0; kk < 8; kk++) {
        short8 a = *(const short8*)(A + (w * 16 + col) * As + kk * 32 + q * 8);
        short8 b = *(const short8*)(Wt + col * 256 + kk * 32 + q * 8);
        acc = __builtin_amdgcn_mfma_f32_16x16x32_bf16(a, b, acc, 0, 0, 0);
    }
    if (col < NV) {
#pragma unroll
        for (int i = 0; i < 4; i++)
            Out[(w * 16 + q * 4 + i) * NV + col] = acc[i] + bias[col];
    }
}

// ---------------- blend epilogue (shared) ----------------
__device__ __forceinline__ void blend_out(const float so[][4], const float dn[][5],
                                          int tid, int m0,
                                          float* o_sigma, float* o_r, float* o_g,
                                          float* o_b, float* o_bw)
{
    if (tid < BM) {
        const int s = tid, m = m0 + s;
        const float bw = sigm(dn[s][4]);
        const float sigma = (1.f - bw) * so[s][0] + bw * dn[s][0];
        const float r  = (1.f - bw) * sigm(so[s][1]) + bw * sigm(dn[s][1]);
        const float gg = (1.f - bw) * sigm(so[s][2]) + bw * sigm(dn[s][2]);
        const float bb = (1.f - bw) * sigm(so[s][3]) + bw * sigm(dn[s][3]);
        o_sigma[m] = sigma; o_r[m] = r; o_g[m] = gg; o_b[m] = bb; o_bw[m] = bw;
    }
}

// ---------------- main MLP kernel: enc from global Eg ----------------
__global__ __launch_bounds__(256, 4)
void nerf_mlp_g(const short* __restrict__ Eg, const short* __restrict__ wt,
                const float* __restrict__ sb0, const float* __restrict__ sb1,
                const float* __restrict__ sb2, const float* __restrict__ sb3,
                const float* __restrict__ sb4,
                const float* __restrict__ db0, const float* __restrict__ db1,
                const float* __restrict__ db2, const float* __restrict__ db3,
                const float* __restrict__ db4,
                float* __restrict__ o_sigma, float* __restrict__ o_r,
                float* __restrict__ o_g, float* __restrict__ o_b,
                float* __restrict__ o_bw)
{
    __shared__ short Hb[BM][HS];   // 33.8 KB activations (in-place)
    __shared__ float so[BM][4];
    __shared__ float dn[BM][5];

    const int tid = threadIdx.x;
    const int m0  = blockIdx.x * BM;
    const short* Ag = Eg + (size_t)m0 * 128;

    // static MLP
    layerG<true>(Ag, wt + SW0, sb0, &Hb[0][0], tid);
    layerL<8, true>(&Hb[0][0], HS, wt + SW1, sb1, &Hb[0][0], tid);
    layerL<8, true>(&Hb[0][0], HS, wt + SW2, sb2, &Hb[0][0], tid);
    layerL<8, true>(&Hb[0][0], HS, wt + SW3, sb3, &Hb[0][0], tid);
    head256<4>(&Hb[0][0], HS, wt + SW4, sb4, &so[0][0], tid);
    // dynamic L0's pre-epilogue barrier orders head's Hb reads vs overwrite

    // dynamic MLP
    layerG<true>(Ag, wt + DW0, db0, &Hb[0][0], tid);
    layerL<8, true>(&Hb[0][0], HS, wt + DW1, db1, &Hb[0][0], tid);
    layerL<8, true>(&Hb[0][0], HS, wt + DW2, db2, &Hb[0][0], tid);
    layerL<8, true>(&Hb[0][0], HS, wt + DW3, db3, &Hb[0][0], tid);
    head256<5>(&Hb[0][0], HS, wt + DW4, db4, &dn[0][0], tid);
    __syncthreads();

    blend_out(so, dn, tid, m0, o_sigma, o_r, o_g, o_b, o_bw);
}

// ---------------- fallback MLP kernel: enc computed in LDS ----------------
__global__ __launch_bounds__(256, 3)
void nerf_mlp_l(const float* __restrict__ points, const float* __restrict__ dirsv,
                const float* __restrict__ timev, const short* __restrict__ wt,
                const float* __restrict__ sb0, const float* __restrict__ sb1,
                const float* __restrict__ sb2, const float* __restrict__ sb3,
                const float* __restrict__ sb4,
                const float* __restrict__ db0, const float* __restrict__ db1,
                const float* __restrict__ db2, const float* __restrict__ db3,
                const float* __restrict__ db4,
                float* __restrict__ o_sigma, float* __restrict__ o_r,
                float* __restrict__ o_g, float* __restrict__ o_b,
                float* __restrict__ o_bw)
{
    __shared__ short E[BM][ES];
    __shared__ short Hb[BM][HS];
    __shared__ float so[BM][4];
    __shared__ float dn[BM][5];

    const int tid = threadIdx.x;
    const int m0  = blockIdx.x * BM;

    for (int idx = tid; idx < BM * 128; idx += 256) {
        const int s = idx >> 7, d = idx & 127;
        E[s][d] = f2bf(encval(d, m0 + s, points, dirsv, timev));
    }
    __syncthreads();

    layerL<4, true>(&E[0][0], ES, wt + SW0, sb0, &Hb[0][0], tid);
    layerL<8, true>(&Hb[0][0], HS, wt + SW1, sb1, &Hb[0][0], tid);
    layerL<8, true>(&Hb[0][0], HS, wt + SW2, sb2, &Hb[0][0], tid);
    layerL<8, true>(&Hb[0][0], HS, wt + SW3, sb3, &Hb[0][0], tid);
    head256<4>(&Hb[0][0], HS, wt + SW4, sb4, &so[0][0], tid);

    layerL<4, true>(&E[0][0], ES, wt + DW0, db0, &Hb[0][0], tid);
    layerL<8, true>(&Hb[0][0], HS, wt + DW1, db1, &Hb[0][0], tid);
    layerL<8, true>(&Hb[0][0], HS, wt + DW2, db2, &Hb[0][0], tid);
    layerL<8, true>(&Hb[0][0], HS, wt + DW3, db3, &Hb[0][0], tid);
    head256<5>(&Hb[0][0], HS, wt + DW4, db4, &dn[0][0], tid);
    __syncthreads();

    blend_out(so, dn, tid, m0, o_sigma, o_r, o_g, o_b, o_bw);
}

// ---------------- compositing: one wave per ray, shuffle scan ----------------
__global__ __launch_bounds__(256)
void nerf_comp(const float* __restrict__ zv,
               const float* __restrict__ o_sigma, const float* __restrict__ o_r,
               const float* __restrict__ o_g, const float* __restrict__ o_b,
               const float* __restrict__ o_bw, float* __restrict__ out)
{
    const int ray  = blockIdx.x * 4 + (threadIdx.x >> 6);
    const int lane = threadIdx.x & 63;
    const int base = ray * SAMP;
    const int s0 = 2 * lane, s1 = s0 + 1;

    const float z0 = zv[base + s0];
    const float z1 = zv[base + s1];
    const float z2 = (lane < 63) ? zv[base + s1 + 1] : 0.0f;
    const float d0 = z1 - z0;
    const float d1 = (lane < 63) ? (z2 - z1) : 1e10f;

    const float sg0 = o_sigma[base + s0], sg1 = o_sigma[base + s1];
    const float a0 = 1.0f - expf(-sg0 * d0);
    const float a1 = 1.0f - expf(-sg1 * d1);
    const float f0 = 1.0f - a0 + 1e-10f;
    const float f1 = 1.0f - a1 + 1e-10f;

    float incl = f0 * f1;
#pragma unroll
    for (int dlt = 1; dlt < 64; dlt <<= 1) {
        const float t = __shfl_up(incl, dlt);
        if (lane >= dlt) incl *= t;
    }
    float ex = __shfl_up(incl, 1);
    if (lane == 0) ex = 1.0f;

    const float t0 = ex;
    const float t1 = ex * f0;
    const float w0 = a0 * t0, w1 = a1 * t1;

    const float bw0 = o_bw[base + s0], bw1 = o_bw[base + s1];
    out[OUT_W  + base + s0] = w0;               out[OUT_W  + base + s1] = w1;
    out[OUT_SW + base + s0] = (1.f - bw0) * w0; out[OUT_SW + base + s1] = (1.f - bw1) * w1;
    out[OUT_DW + base + s0] = bw0 * w0;         out[OUT_DW + base + s1] = bw1 * w1;

    float pr = w0 * o_r[base + s0] + w1 * o_r[base + s1];
    float pg = w0 * o_g[base + s0] + w1 * o_g[base + s1];
    float pb = w0 * o_b[base + s0] + w1 * o_b[base + s1];
    float pd = w0 * z0 + w1 * z1;
#pragma unroll
    for (int dlt = 32; dlt >= 1; dlt >>= 1) {
        pr += __shfl_down(pr, dlt);
        pg += __shfl_down(pg, dlt);
        pb += __shfl_down(pb, dlt);
        pd += __shfl_down(pd, dlt);
    }
    if (lane == 0) {
        out[OUT_RGB + ray * 3 + 0] = pr;
        out[OUT_RGB + ray * 3 + 1] = pg;
        out[OUT_RGB + ray * 3 + 2] = pb;
        out[OUT_DEPTH + ray] = pd;
    }
}

extern "C" void kernel_launch(void* const* d_in, const int* in_sizes, int n_in,
                              void* d_out, int out_size, void* d_ws, size_t ws_size,
                              hipStream_t stream)
{
    const float* points = (const float*)d_in[0];
    const float* dirsv  = (const float*)d_in[1];
    const float* zvals  = (const float*)d_in[2];
    const float* timev  = (const float*)d_in[3];

    const float *sW[5], *sb[5], *dW[5], *db[5];
    if (in_sizes[6] == 99 * 256) {
        for (int i = 0; i < 5; i++) {   // interleaved (sW_i, sb_i, dW_i, db_i)
            sW[i] = (const float*)d_in[4 + 4 * i + 0];
            sb[i] = (const float*)d_in[4 + 4 * i + 1];
            dW[i] = (const float*)d_in[4 + 4 * i + 2];
            db[i] = (const float*)d_in[4 + 4 * i + 3];
        }
    } else {
        for (int i = 0; i < 5; i++) {   // all static then all dynamic
            sW[i] = (const float*)d_in[4 + 2 * i + 0];
            sb[i] = (const float*)d_in[4 + 2 * i + 1];
            dW[i] = (const float*)d_in[14 + 2 * i + 0];
            db[i] = (const float*)d_in[14 + 2 * i + 1];
        }
    }

    // ws layout: wt bf16 weights | Eg bf16 [MTOT][128] | 5 fp32 per-sample arrays
    const size_t wt_bytes = (size_t)WTOT * 2;                    // 933,888 (16B-mult)
    const size_t eg_bytes = (size_t)MTOT * 128 * 2;              // 67,108,864
    const size_t f_bytes  = (size_t)MTOT * 5 * 4;                // 5,242,880
    const bool   big_ws   = ws_size >= wt_bytes + eg_bytes + f_bytes;

    short* wt = (short*)d_ws;
    short* Eg = (short*)((char*)d_ws + wt_bytes);
    float* ws = (float*)((char*)d_ws + wt_bytes + (big_ws ? eg_bytes : 0));
    float* o_sigma = ws;
    float* o_r  = ws + (size_t)MTOT * 1;
    float* o_g  = ws + (size_t)MTOT * 2;
    float* o_b  = ws + (size_t)MTOT * 3;
    float* o_bw = ws + (size_t)MTOT * 4;

    prep_weights<<<(WTOT + 255) / 256, 256, 0, stream>>>(
        sW[0], sW[1], sW[2], sW[3], sW[4], dW[0], dW[1], dW[2], dW[3], dW[4], wt);

    if (big_ws) {
        nerf_enc<<<MTOT * 64 / 256, 256, 0, stream>>>(points, dirsv, timev, Eg);
        nerf_mlp_g<<<MTOT / BM, 256, 0, stream>>>(Eg, wt,
            sb[0], sb[1], sb[2], sb[3], sb[4], db[0], db[1], db[2], db[3], db[4],
            o_sigma, o_r, o_g, o_b, o_bw);
    } else {
        nerf_mlp_l<<<MTOT / BM, 256, 0, stream>>>(points, dirsv, timev, wt,
            sb[0], sb[1], sb[2], sb[3], sb[4], db[0], db[1], db[2], db[3], db[4],
            o_sigma, o_r, o_g, o_b, o_bw);
    }

    nerf_comp<<<RAYS / 4, 256, 0, stream>>>(zvals, o_sigma, o_r, o_g, o_b, o_bw,
                                            (float*)d_out);
}

// Round 5
// 772.705 us; speedup vs baseline: 1.0084x; 1.0084x over previous
//
#include <hip/hip_runtime.h>
#include <math.h>

// FusionNeRF round 5: R4 design with the spill fixed.
//   R4's __launch_bounds__(256,4) forced <=128 unified regs/wave -> compiler
//   spilled the MFMA fragments to scratch (258 MB WRITE_SIZE, 482 MB HBM
//   round-trip = entire kernel duration). Revert to (256,3): ~170-reg budget,
//   no spill (R2 measured 84 VGPR + 64 AGPR under the same bound).
//  - nerf_enc: positional encodings -> global bf16 Eg[M][128]
//  - nerf_mlp_g: MFMA MLP, layer0 A from global Eg, LDS = 36.1 KB.
//    Swapped-operand MFMA (D^T) => packed ds_write_b64 epilogue.
//  - nerf_mlp_l: fallback (enc in LDS) if ws_size too small for Eg.
//  - nerf_comp: wave-per-ray shuffle-scan compositing.

#define RAYS 2048
#define SAMP 128
#define MTOT (RAYS * SAMP)
#define HD   256
#define BM   64              // samples per block
#define ES   136             // enc LDS stride (fallback kernel)
#define HS   264             // hidden LDS stride (bf16), 256 + 8 pad

#define OUT_RGB   0
#define OUT_DEPTH 6144
#define OUT_W     8192
#define OUT_SW    270336
#define OUT_DW    532480

// bf16 weight workspace offsets (elements)
#define SW0 0
#define SW1 32768
#define SW2 98304
#define SW3 163840
#define SW4 229376
#define DW0 233472
#define DW1 266240
#define DW2 331776
#define DW3 397312
#define DW4 462848
#define WTOT 466944

typedef __attribute__((ext_vector_type(8))) short short8;
typedef __attribute__((ext_vector_type(4))) float f32x4;

__device__ __forceinline__ float sigm(float x) { return 1.0f / (1.0f + expf(-x)); }

__device__ __forceinline__ unsigned bfbits(float f) {  // RNE fp32 -> bf16 bits
    union { float f; unsigned u; } v; v.f = f;
    unsigned r = v.u + 0x7fffu + ((v.u >> 16) & 1u);
    return r >> 16;
}
__device__ __forceinline__ short f2bf(float f) { return (short)bfbits(f); }
__device__ __forceinline__ unsigned pk2(float a, float b) {  // packed bf16 pair (a=low)
    return bfbits(a) | (bfbits(b) << 16);
}

// ---------------- weight prep: W[K][N] fp32 -> Wt[Npad][Kpad] bf16 ----------------
__device__ __forceinline__ void conv1(const float* __restrict__ src, short* __restrict__ dst,
                                      int local, int K, int N, int Kpad) {
    const int n = local / Kpad, k = local - n * Kpad;
    const float v = (k < K && n < N) ? src[k * N + n] : 0.0f;
    dst[local] = f2bf(v);
}

__global__ __launch_bounds__(256)
void prep_weights(const float* sW0, const float* sW1, const float* sW2,
                  const float* sW3, const float* sW4,
                  const float* dW0, const float* dW1, const float* dW2,
                  const float* dW3, const float* dW4, short* __restrict__ dst)
{
    const int idx = blockIdx.x * 256 + threadIdx.x;
    if (idx >= WTOT) return;
    if      (idx < SW1) conv1(sW0, dst + SW0, idx - SW0,  90, 256, 128);
    else if (idx < SW2) conv1(sW1, dst + SW1, idx - SW1, 256, 256, 256);
    else if (idx < SW3) conv1(sW2, dst + SW2, idx - SW2, 256, 256, 256);
    else if (idx < SW4) conv1(sW3, dst + SW3, idx - SW3, 256, 256, 256);
    else if (idx < DW0) conv1(sW4, dst + SW4, idx - SW4, 256,   4, 256);
    else if (idx < DW1) conv1(dW0, dst + DW0, idx - DW0,  99, 256, 128);
    else if (idx < DW2) conv1(dW1, dst + DW1, idx - DW1, 256, 256, 256);
    else if (idx < DW3) conv1(dW2, dst + DW2, idx - DW2, 256, 256, 256);
    else if (idx < DW4) conv1(dW3, dst + DW3, idx - DW3, 256, 256, 256);
    else                conv1(dW4, dst + DW4, idx - DW4, 256,   5, 256);
}

// ---------------- positional encoding value ----------------
__device__ __forceinline__ float encval(int d, int m,
                                        const float* __restrict__ points,
                                        const float* __restrict__ dirsv,
                                        const float* __restrict__ timev)
{
    float v = 0.0f;
    if (d < 3) {
        v = points[m * 3 + d];
    } else if (d < 63) {
        int qq = d - 3;
        const int l = qq / 6, r = qq - l * 6;
        const int c = (r < 3) ? r : r - 3;
        const float x = points[m * 3 + c] * (float)(1 << l);
        v = (r < 3) ? sinf(x) : cosf(x);
    } else if (d < 90) {
        int qq = d - 63;
        if (qq < 3) v = dirsv[m * 3 + qq];
        else {
            qq -= 3;
            const int l = qq / 6, r = qq - l * 6;
            const int c = (r < 3) ? r : r - 3;
            const float x = dirsv[m * 3 + c] * (float)(1 << l);
            v = (r < 3) ? sinf(x) : cosf(x);
        }
    } else if (d < 99) {
        int qq = d - 90;
        const float t = timev[m];
        if (qq == 0) v = t;
        else {
            qq -= 1;
            const float x = t * (float)(1 << (qq >> 1));
            v = ((qq & 1) == 0) ? sinf(x) : cosf(x);
        }
    }
    return v;
}

__global__ __launch_bounds__(256)
void nerf_enc(const float* __restrict__ points, const float* __restrict__ dirsv,
              const float* __restrict__ timev, short* __restrict__ Eg)
{
    const int idx = blockIdx.x * 256 + threadIdx.x;   // one per (m, d-pair)
    if (idx >= MTOT * 64) return;
    const int m = idx >> 6, dp = idx & 63;
    const float v0 = encval(2 * dp,     m, points, dirsv, timev);
    const float v1 = encval(2 * dp + 1, m, points, dirsv, timev);
    *(unsigned*)(Eg + (size_t)m * 128 + 2 * dp) = pk2(v0, v1);
}

// ---------------- epilogue: D^T accumulators -> Hb[m][n] packed b64 stores ----------------
template <bool RELU>
__device__ __forceinline__ void epilogue(f32x4 acc[4][4], const float* __restrict__ bias,
                                         short* O, int w, int q, int col)
{
    float4 bv[4];
#pragma unroll
    for (int nt = 0; nt < 4; nt++)
        bv[nt] = *(const float4*)(bias + w * 64 + nt * 16 + q * 4);
#pragma unroll
    for (int mt = 0; mt < 4; mt++) {
        short* dst = O + (mt * 16 + col) * HS + w * 64 + q * 4;
#pragma unroll
        for (int nt = 0; nt < 4; nt++) {
            float v0 = acc[mt][nt][0] + bv[nt].x;
            float v1 = acc[mt][nt][1] + bv[nt].y;
            float v2 = acc[mt][nt][2] + bv[nt].z;
            float v3 = acc[mt][nt][3] + bv[nt].w;
            if (RELU) {
                v0 = fmaxf(v0, 0.f); v1 = fmaxf(v1, 0.f);
                v2 = fmaxf(v2, 0.f); v3 = fmaxf(v3, 0.f);
            }
            uint2 p; p.x = pk2(v0, v1); p.y = pk2(v2, v3);
            *(uint2*)(dst + nt * 16) = p;
        }
    }
}

// A from LDS (stride As). Swapped-operand MFMA: acc = D^T tiles.
template <int KSTEPS, bool RELU>
__device__ __forceinline__ void layerL(const short* A, int As,
                                       const short* __restrict__ Wt,
                                       const float* __restrict__ bias,
                                       short* O, int tid)
{
    const int w = tid >> 6, lane = tid & 63, q = lane >> 4, col = lane & 15;
    const int K = KSTEPS * 32;
    f32x4 acc[4][4];
#pragma unroll
    for (int mt = 0; mt < 4; mt++)
#pragma unroll
        for (int nt = 0; nt < 4; nt++) acc[mt][nt] = (f32x4)0.0f;

    const short* wbase = Wt + (size_t)(w * 64) * K + q * 8;
#pragma unroll
    for (int kk = 0; kk < KSTEPS; kk++) {
        short8 a[4], b[4];
#pragma unroll
        for (int mt = 0; mt < 4; mt++)
            a[mt] = *(const short8*)(A + (mt * 16 + col) * As + kk * 32 + q * 8);
#pragma unroll
        for (int nt = 0; nt < 4; nt++)
            b[nt] = *(const short8*)(wbase + (size_t)(nt * 16 + col) * K + kk * 32);
#pragma unroll
        for (int mt = 0; mt < 4; mt++)
#pragma unroll
            for (int nt = 0; nt < 4; nt++)
                acc[mt][nt] = __builtin_amdgcn_mfma_f32_16x16x32_bf16(b[nt], a[mt], acc[mt][nt], 0, 0, 0);
    }
    __syncthreads();                       // all waves done reading A (A may alias O)
    epilogue<RELU>(acc, bias, O, w, q, col);
    __syncthreads();                       // O visible to next layer
}

// A from global (stride 128, Kpad=128 => KSTEPS=4).
template <bool RELU>
__device__ __forceinline__ void layerG(const short* __restrict__ Ag,
                                       const short* __restrict__ Wt,
                                       const float* __restrict__ bias,
                                       short* O, int tid)
{
    const int w = tid >> 6, lane = tid & 63, q = lane >> 4, col = lane & 15;
    f32x4 acc[4][4];
#pragma unroll
    for (int mt = 0; mt < 4; mt++)
#pragma unroll
        for (int nt = 0; nt < 4; nt++) acc[mt][nt] = (f32x4)0.0f;

    const short* wbase = Wt + (size_t)(w * 64) * 128 + q * 8;
#pragma unroll
    for (int kk = 0; kk < 4; kk++) {
        short8 a[4], b[4];
#pragma unroll
        for (int mt = 0; mt < 4; mt++)
            a[mt] = *(const short8*)(Ag + (size_t)(mt * 16 + col) * 128 + kk * 32 + q * 8);
#pragma unroll
        for (int nt = 0; nt < 4; nt++)
            b[nt] = *(const short8*)(wbase + (size_t)(nt * 16 + col) * 128 + kk * 32);
#pragma unroll
        for (int mt = 0; mt < 4; mt++)
#pragma unroll
            for (int nt = 0; nt < 4; nt++)
                acc[mt][nt] = __builtin_amdgcn_mfma_f32_16x16x32_bf16(b[nt], a[mt], acc[mt][nt], 0, 0, 0);
    }
    __syncthreads();                       // prior readers of O (e.g. static head) done
    epilogue<RELU>(acc, bias, O, w, q, col);
    __syncthreads();
}

// head: A[64][256] @ Wt[16][256]^T -> Out[64][NV] (+bias); normal operand order.
template <int NV>
__device__ __forceinline__ void head256(const short* A, int As,
                                        const short* __restrict__ Wt,
                                        const float* __restrict__ bias,
                                        float* Out, int tid)
{
    const int w = tid >> 6, lane = tid & 63, q = lane >> 4, col = lane & 15;
    f32x4 acc = (f32x4)0.0f;
#pragma unroll
    for (int kk = 0; kk < 8; kk++) {
        short8 a = *(const short8*)(A + (w * 16 + col) * As + kk * 32 + q * 8);
        short8 b = *(const short8*)(Wt + col * 256 + kk * 32 + q * 8);
        acc = __builtin_amdgcn_mfma_f32_16x16x32_bf16(a, b, acc, 0, 0, 0);
    }
    if (col < NV) {
#pragma unroll
        for (int i = 0; i < 4; i++)
            Out[(w * 16 + q * 4 + i) * NV + col] = acc[i] + bias[col];
    }
}

// ---------------- blend epilogue (shared) ----------------
__device__ __forceinline__ void blend_out(const float so[][4], const float dn[][5],
                                          int tid, int m0,
                                          float* o_sigma, float* o_r, float* o_g,
                                          float* o_b, float* o_bw)
{
    if (tid < BM) {
        const int s = tid, m = m0 + s;
        const float bw = sigm(dn[s][4]);
        const float sigma = (1.f - bw) * so[s][0] + bw * dn[s][0];
        const float r  = (1.f - bw) * sigm(so[s][1]) + bw * sigm(dn[s][1]);
        const float gg = (1.f - bw) * sigm(so[s][2]) + bw * sigm(dn[s][2]);
        const float bb = (1.f - bw) * sigm(so[s][3]) + bw * sigm(dn[s][3]);
        o_sigma[m] = sigma; o_r[m] = r; o_g[m] = gg; o_b[m] = bb; o_bw[m] = bw;
    }
}

// ---------------- main MLP kernel: enc from global Eg ----------------
// (256,3): 3 waves/EU -> ~170-reg budget -> NO scratch spill (the R4 (256,4)
// variant spilled ~15 KB/wave -> 482 MB HBM traffic that WAS the runtime).
__global__ __launch_bounds__(256, 3)
void nerf_mlp_g(const short* __restrict__ Eg, const short* __restrict__ wt,
                const float* __restrict__ sb0, const float* __restrict__ sb1,
                const float* __restrict__ sb2, const float* __restrict__ sb3,
                const float* __restrict__ sb4,
                const float* __restrict__ db0, const float* __restrict__ db1,
                const float* __restrict__ db2, const float* __restrict__ db3,
                const float* __restrict__ db4,
                float* __restrict__ o_sigma, float* __restrict__ o_r,
                float* __restrict__ o_g, float* __restrict__ o_b,
                float* __restrict__ o_bw)
{
    __shared__ short Hb[BM][HS];   // 33.8 KB activations (in-place)
    __shared__ float so[BM][4];
    __shared__ float dn[BM][5];

    const int tid = threadIdx.x;
    const int m0  = blockIdx.x * BM;
    const short* Ag = Eg + (size_t)m0 * 128;

    // static MLP
    layerG<true>(Ag, wt + SW0, sb0, &Hb[0][0], tid);
    layerL<8, true>(&Hb[0][0], HS, wt + SW1, sb1, &Hb[0][0], tid);
    layerL<8, true>(&Hb[0][0], HS, wt + SW2, sb2, &Hb[0][0], tid);
    layerL<8, true>(&Hb[0][0], HS, wt + SW3, sb3, &Hb[0][0], tid);
    head256<4>(&Hb[0][0], HS, wt + SW4, sb4, &so[0][0], tid);
    // dynamic L0's pre-epilogue barrier orders head's Hb reads vs overwrite

    // dynamic MLP
    layerG<true>(Ag, wt + DW0, db0, &Hb[0][0], tid);
    layerL<8, true>(&Hb[0][0], HS, wt + DW1, db1, &Hb[0][0], tid);
    layerL<8, true>(&Hb[0][0], HS, wt + DW2, db2, &Hb[0][0], tid);
    layerL<8, true>(&Hb[0][0], HS, wt + DW3, db3, &Hb[0][0], tid);
    head256<5>(&Hb[0][0], HS, wt + DW4, db4, &dn[0][0], tid);
    __syncthreads();

    blend_out(so, dn, tid, m0, o_sigma, o_r, o_g, o_b, o_bw);
}

// ---------------- fallback MLP kernel: enc computed in LDS ----------------
__global__ __launch_bounds__(256, 3)
void nerf_mlp_l(const float* __restrict__ points, const float* __restrict__ dirsv,
                const float* __restrict__ timev, const short* __restrict__ wt,
                const float* __restrict__ sb0, const float* __restrict__ sb1,
                const float* __restrict__ sb2, const float* __restrict__ sb3,
                const float* __restrict__ sb4,
                const float* __restrict__ db0, const float* __restrict__ db1,
                const float* __restrict__ db2, const float* __restrict__ db3,
                const float* __restrict__ db4,
                float* __restrict__ o_sigma, float* __restrict__ o_r,
                float* __restrict__ o_g, float* __restrict__ o_b,
                float* __restrict__ o_bw)
{
    __shared__ short E[BM][ES];
    __shared__ short Hb[BM][HS];
    __shared__ float so[BM][4];
    __shared__ float dn[BM][5];

    const int tid = threadIdx.x;
    const int m0  = blockIdx.x * BM;

    for (int idx = tid; idx < BM * 128; idx += 256) {
        const int s = idx >> 7, d = idx & 127;
        E[s][d] = f2bf(encval(d, m0 + s, points, dirsv, timev));
    }
    __syncthreads();

    layerL<4, true>(&E[0][0], ES, wt + SW0, sb0, &Hb[0][0], tid);
    layerL<8, true>(&Hb[0][0], HS, wt + SW1, sb1, &Hb[0][0], tid);
    layerL<8, true>(&Hb[0][0], HS, wt + SW2, sb2, &Hb[0][0], tid);
    layerL<8, true>(&Hb[0][0], HS, wt + SW3, sb3, &Hb[0][0], tid);
    head256<4>(&Hb[0][0], HS, wt + SW4, sb4, &so[0][0], tid);

    layerL<4, true>(&E[0][0], ES, wt + DW0, db0, &Hb[0][0], tid);
    layerL<8, true>(&Hb[0][0], HS, wt + DW1, db1, &Hb[0][0], tid);
    layerL<8, true>(&Hb[0][0], HS, wt + DW2, db2, &Hb[0][0], tid);
    layerL<8, true>(&Hb[0][0], HS, wt + DW3, db3, &Hb[0][0], tid);
    head256<5>(&Hb[0][0], HS, wt + DW4, db4, &dn[0][0], tid);
    __syncthreads();

    blend_out(so, dn, tid, m0, o_sigma, o_r, o_g, o_b, o_bw);
}

// ---------------- compositing: one wave per ray, shuffle scan ----------------
__global__ __launch_bounds__(256)
void nerf_comp(const float* __restrict__ zv,
               const float* __restrict__ o_sigma, const float* __restrict__ o_r,
               const float* __restrict__ o_g, const float* __restrict__ o_b,
               const float* __restrict__ o_bw, float* __restrict__ out)
{
    const int ray  = blockIdx.x * 4 + (threadIdx.x >> 6);
    const int lane = threadIdx.x & 63;
    const int base = ray * SAMP;
    const int s0 = 2 * lane, s1 = s0 + 1;

    const float z0 = zv[base + s0];
    const float z1 = zv[base + s1];
    const float z2 = (lane < 63) ? zv[base + s1 + 1] : 0.0f;
    const float d0 = z1 - z0;
    const float d1 = (lane < 63) ? (z2 - z1) : 1e10f;

    const float sg0 = o_sigma[base + s0], sg1 = o_sigma[base + s1];
    const float a0 = 1.0f - expf(-sg0 * d0);
    const float a1 = 1.0f - expf(-sg1 * d1);
    const float f0 = 1.0f - a0 + 1e-10f;
    const float f1 = 1.0f - a1 + 1e-10f;

    float incl = f0 * f1;
#pragma unroll
    for (int dlt = 1; dlt < 64; dlt <<= 1) {
        const float t = __shfl_up(incl, dlt);
        if (lane >= dlt) incl *= t;
    }
    float ex = __shfl_up(incl, 1);
    if (lane == 0) ex = 1.0f;

    const float t0 = ex;
    const float t1 = ex * f0;
    const float w0 = a0 * t0, w1 = a1 * t1;

    const float bw0 = o_bw[base + s0], bw1 = o_bw[base + s1];
    out[OUT_W  + base + s0] = w0;               out[OUT_W  + base + s1] = w1;
    out[OUT_SW + base + s0] = (1.f - bw0) * w0; out[OUT_SW + base + s1] = (1.f - bw1) * w1;
    out[OUT_DW + base + s0] = bw0 * w0;         out[OUT_DW + base + s1] = bw1 * w1;

    float pr = w0 * o_r[base + s0] + w1 * o_r[base + s1];
    float pg = w0 * o_g[base + s0] + w1 * o_g[base + s1];
    float pb = w0 * o_b[base + s0] + w1 * o_b[base + s1];
    float pd = w0 * z0 + w1 * z1;
#pragma unroll
    for (int dlt = 32; dlt >= 1; dlt >>= 1) {
        pr += __shfl_down(pr, dlt);
        pg += __shfl_down(pg, dlt);
        pb += __shfl_down(pb, dlt);
        pd += __shfl_down(pd, dlt);
    }
    if (lane == 0) {
        out[OUT_RGB + ray * 3 + 0] = pr;
        out[OUT_RGB + ray * 3 + 1] = pg;
        out[OUT_RGB + ray * 3 + 2] = pb;
        out[OUT_DEPTH + ray] = pd;
    }
}

extern "C" void kernel_launch(void* const* d_in, const int* in_sizes, int n_in,
                              void* d_out, int out_size, void* d_ws, size_t ws_size,
                              hipStream_t stream)
{
    const float* points = (const float*)d_in[0];
    const float* dirsv  = (const float*)d_in[1];
    const float* zvals  = (const float*)d_in[2];
    const float* timev  = (const float*)d_in[3];

    const float *sW[5], *sb[5], *dW[5], *db[5];
    if (in_sizes[6] == 99 * 256) {
        for (int i = 0; i < 5; i++) {   // interleaved (sW_i, sb_i, dW_i, db_i)
            sW[i] = (const float*)d_in[4 + 4 * i + 0];
            sb[i] = (const float*)d_in[4 + 4 * i + 1];
            dW[i] = (const float*)d_in[4 + 4 * i + 2];
            db[i] = (const float*)d_in[4 + 4 * i + 3];
        }
    } else {
        for (int i = 0; i < 5; i++) {   // all static then all dynamic
            sW[i] = (const float*)d_in[4 + 2 * i + 0];
            sb[i] = (const float*)d_in[4 + 2 * i + 1];
            dW[i] = (const float*)d_in[14 + 2 * i + 0];
            db[i] = (const float*)d_in[14 + 2 * i + 1];
        }
    }

    // ws layout: wt bf16 weights | Eg bf16 [MTOT][128] | 5 fp32 per-sample arrays
    const size_t wt_bytes = (size_t)WTOT * 2;                    // 933,888 (16B-mult)
    const size_t eg_bytes = (size_t)MTOT * 128 * 2;              // 67,108,864
    const size_t f_bytes  = (size_t)MTOT * 5 * 4;                // 5,242,880
    const bool   big_ws   = ws_size >= wt_bytes + eg_bytes + f_bytes;

    short* wt = (short*)d_ws;
    short* Eg = (short*)((char*)d_ws + wt_bytes);
    float* ws = (float*)((char*)d_ws + wt_bytes + (big_ws ? eg_bytes : 0));
    float* o_sigma = ws;
    float* o_r  = ws + (size_t)MTOT * 1;
    float* o_g  = ws + (size_t)MTOT * 2;
    float* o_b  = ws + (size_t)MTOT * 3;
    float* o_bw = ws + (size_t)MTOT * 4;

    prep_weights<<<(WTOT + 255) / 256, 256, 0, stream>>>(
        sW[0], sW[1], sW[2], sW[3], sW[4], dW[0], dW[1], dW[2], dW[3], dW[4], wt);

    if (big_ws) {
        nerf_enc<<<MTOT * 64 / 256, 256, 0, stream>>>(points, dirsv, timev, Eg);
        nerf_mlp_g<<<MTOT / BM, 256, 0, stream>>>(Eg, wt,
            sb[0], sb[1], sb[2], sb[3], sb[4], db[0], db[1], db[2], db[3], db[4],
            o_sigma, o_r, o_g, o_b, o_bw);
    } else {
        nerf_mlp_l<<<MTOT / BM, 256, 0, stream>>>(points, dirsv, timev, wt,
            sb[0], sb[1], sb[2], sb[3], sb[4], db[0], db[1], db[2], db[3], db[4],
            o_sigma, o_r, o_g, o_b, o_bw);
    }

    nerf_comp<<<RAYS / 4, 256, 0, stream>>>(zvals, o_sigma, o_r, o_g, o_b, o_bw,
                                            (float*)d_out);
}